// Round 4
// baseline (156.116 us; speedup 1.0000x reference)
//
#include <hip/hip_runtime.h>

#define NTRAIN 32768
#define NBDY   4096
#define PHYS_WPROB (NTRAIN / 16)      // 2048 one-wave physics problems
#define BDY_WPROB  (4 * NBDY / 64)    // 256 one-wave boundary problems (64 pts)
#define LDS_BYTES  (64 * 136 * 2)     // 17,408 B private slice per 1-wave block

typedef _Float16 f16x8 __attribute__((ext_vector_type(8)));
typedef __fp16   fp16x2 __attribute__((ext_vector_type(2)));
typedef float    f32x4 __attribute__((ext_vector_type(4)));

union FragU { uint4 q; f16x8 b; _Float16 e[8]; };
union F4  { float4 v; float f[4]; };
union H2  { fp16x2 h; _Float16 e[2]; unsigned int u; };

__device__ __forceinline__ float fast_tanh(float z) {
    float e = __expf(2.0f * z);
    return 1.0f - 2.0f * __builtin_amdgcn_rcpf(e + 1.0f);
}

__device__ __forceinline__ unsigned int pk2(float a, float b) {
    H2 r; r.h = __builtin_amdgcn_cvt_pkrtz(a, b);
    return r.u;
}

// ---------------------------------------------------------------------------
// Pack weights into MFMA A-fragment order (fp16 hi+lo).  (unchanged)
// W1..W3: hi at wsU + l*32768, lo at +16384 (lo unused by fused hidden layers).
// V1-hi at wsU+98304. W4 padded 128x16: hi at wsU+102400, lo +2048.
// Block 24 zeroes out[0].
// ---------------------------------------------------------------------------
__global__ __launch_bounds__(256) void pack_w_kernel(
    const float* __restrict__ W1, const float* __restrict__ W2,
    const float* __restrict__ W3, const float* __restrict__ V1,
    const float* __restrict__ W4,
    unsigned short* __restrict__ wsU, float* __restrict__ out)
{
    int b = blockIdx.x;
    if (b < 24) {
        int mat = b >> 3, rb = b & 7;          // 16 rows per block
        const float* W = (mat == 0) ? W1 : (mat == 1) ? W2 : W3;
        unsigned int* hiU = (unsigned int*)(wsU + mat * 32768);
        unsigned int* loU = hiU + 8192;
        int n   = threadIdx.x & 127;
        int pr0 = threadIdx.x >> 7;
        #pragma unroll
        for (int it = 0; it < 4; it++) {
            int pr = pr0 + 2 * it;
            int k  = rb * 16 + pr * 2;
            float v0 = W[k * 128 + n];
            float v1 = W[(k + 1) * 128 + n];
            H2 hh, ll;
            hh.e[0] = (_Float16)v0;
            hh.e[1] = (_Float16)v1;
            ll.e[0] = (_Float16)(v0 - (float)hh.e[0]);
            ll.e[1] = (_Float16)(v1 - (float)hh.e[1]);
            int base = ((n >> 4) * 4 + (k >> 5)) * 64 + ((k >> 3) & 3) * 16 + (n & 15);
            int uoff = base * 4 + ((k & 7) >> 1);
            hiU[uoff] = hh.u;
            loU[uoff] = ll.u;
        }
    } else if (b == 24) {
        unsigned int* hiU = (unsigned int*)(wsU + 98304);
        int n   = threadIdx.x & 63;
        int pr0 = threadIdx.x >> 6;
        #pragma unroll
        for (int it = 0; it < 8; it++) {
            int pr = pr0 + 4 * it;
            int k  = pr * 2;
            float v0 = V1[k * 64 + n];
            float v1 = V1[(k + 1) * 64 + n];
            H2 hh;
            hh.e[0] = (_Float16)v0;
            hh.e[1] = (_Float16)v1;
            int base = ((n >> 4) * 2 + (k >> 5)) * 64 + ((k >> 3) & 3) * 16 + (n & 15);
            hiU[base * 4 + ((k & 7) >> 1)] = hh.u;
        }
        if (threadIdx.x == 0) out[0] = 0.f;
    } else {
        _Float16* hi = (_Float16*)(wsU + 102400);
        _Float16* lo = hi + 2048;
        int u4 = threadIdx.x;
        int lane = u4 & 63, ks = u4 >> 6;
        int m  = lane & 15;
        int kb = ks * 32 + ((lane >> 4) << 3);
        FragU fh, fl;
        #pragma unroll
        for (int j = 0; j < 8; j++) {
            float v = (m < 4) ? W4[(kb + j) * 4 + m] : 0.f;
            _Float16 h = (_Float16)v;
            fh.e[j] = h;
            fl.e[j] = (_Float16)(v - (float)h);
        }
        *(uint4*)(hi + u4 * 8) = fh.q;
        *(uint4*)(lo + u4 * 8) = fl.q;
    }
}

// ---------------------------------------------------------------------------
// Fused kernel, r21: BARRIER-FREE wave-private problems.
// One 64-thread block = one wave = one complete problem:
//   physics: 16 pts, A-slice 64 rows (4 streams x 16 pts) x 136 ushorts
//   boundary: 64 pts, A-slice 64 rows (4 pt-tiles x 16) x 136
// All cross-stream combines are lane-local (row-tile == stream). L4 outputs,
// mu, and residual live in registers; biases read from L1 per-epilogue.
// ZERO __syncthreads: same-wave LDS ordering via in-order DS + lgkmcnt.
// Each wave reads full W per layer from L1 (shared, read-only, L1-hit).
// 2304 blocks -> 9 resident waves/CU (LDS-capped), perfectly balanced.
// ---------------------------------------------------------------------------
__global__ __launch_bounds__(64, 3) void fused_kernel(
    const float* __restrict__ xt,
    const float* __restrict__ x_inlet, const float* __restrict__ U_inlet,
    const float* __restrict__ x_base,  const float* __restrict__ x_top,
    const float* __restrict__ x_slip,
    const float* __restrict__ W0, const float* __restrict__ b0,
    const float* __restrict__ W1, const float* __restrict__ b1,
    const float* __restrict__ W2, const float* __restrict__ b2,
    const float* __restrict__ W3, const float* __restrict__ b3,
    const float* __restrict__ W4, const float* __restrict__ b4,
    const float* __restrict__ V0, const float* __restrict__ c0,
    const float* __restrict__ V1, const float* __restrict__ c1,
    const float* __restrict__ V2, const float* __restrict__ c2,
    const unsigned short* __restrict__ wsU,
    float* __restrict__ out)
{
    extern __shared__ char SMC[];
    unsigned short* A = (unsigned short*)SMC;   // 64 rows x 136 ushorts
    const int lane = threadIdx.x;
    const int nn   = lane & 15;
    const int q    = lane >> 4;

    if (blockIdx.x < PHYS_WPROB) {
        // =================== PHYSICS (16 pts per wave) ===================
        const int pt = blockIdx.x * 16 + nn;
        const float2 xy = *(const float2*)(xt + pt * 2);

        // ---- mu net, fully wave-local: result replicated across q ----
        float mu;
        {
            FragU mb[2];
            #pragma unroll
            for (int ks = 0; ks < 2; ks++) {
                int u0 = ks * 32 + q * 8;
                F4 va0, va1, vb0, vb1, cc0, cc1;
                va0.v = *(const float4*)(V0 + u0);
                va1.v = *(const float4*)(V0 + u0 + 4);
                vb0.v = *(const float4*)(V0 + 64 + u0);
                vb1.v = *(const float4*)(V0 + 64 + u0 + 4);
                cc0.v = *(const float4*)(c0 + u0);
                cc1.v = *(const float4*)(c0 + u0 + 4);
                #pragma unroll
                for (int i = 0; i < 4; i++) {
                    mb[ks].e[i]     = (_Float16)fast_tanh(
                        xy.x * va0.f[i] + xy.y * vb0.f[i] + cc0.f[i]);
                    mb[ks].e[4 + i] = (_Float16)fast_tanh(
                        xy.x * va1.f[i] + xy.y * vb1.f[i] + cc1.f[i]);
                }
            }
            float partial = 0.f;
            #pragma unroll
            for (int tu = 0; tu < 4; tu++) {
                f32x4 macc = {0.f, 0.f, 0.f, 0.f};
                #pragma unroll
                for (int ks = 0; ks < 2; ks++) {
                    FragU vh;
                    vh.q = *(const uint4*)(wsU + 98304 +
                           (((tu * 2 + ks) * 64 + lane) << 3));
                    macc = __builtin_amdgcn_mfma_f32_16x16x32_f16(vh.b, mb[ks].b, macc, 0, 0, 0);
                }
                int u2 = tu * 16 + q * 4;
                F4 cv, w2;
                cv.v = *(const float4*)(c1 + u2);
                w2.v = *(const float4*)(V2 + u2);
                #pragma unroll
                for (int r = 0; r < 4; r++)
                    partial += fast_tanh(macc[r] + cv.f[r]) * w2.f[r];
            }
            partial += __shfl_xor(partial, 16);
            partial += __shfl_xor(partial, 32);
            float s = partial + c2[0];
            mu = 0.01f * s * s;
        }

        // ---- layer 0: lane (nn,q) -> pt nn, units q*32..q*32+31 ----
        #pragma unroll
        for (int j4 = 0; j4 < 4; j4++) {
            float vals[4][8];
            #pragma unroll
            for (int j = 0; j < 8; j++) {
                int u = q * 32 + j4 * 8 + j;
                float w0 = W0[u], w1 = W0[128 + u];
                float zv = xy.x * w0 + xy.y * w1 + b0[u];
                float tt = fast_tanh(zv);
                float s2 = 1.f - tt * tt;
                float m2 = -2.f * tt * s2;
                vals[0][j] = tt;
                vals[1][j] = s2 * w0;
                vals[2][j] = s2 * w1;
                vals[3][j] = m2 * (w0 * w0 + w1 * w1);  // z_lap = 0 at layer 0
            }
            #pragma unroll
            for (int s = 0; s < 4; s++) {
                uint4 d = make_uint4(pk2(vals[s][0], vals[s][1]),
                                     pk2(vals[s][2], vals[s][3]),
                                     pk2(vals[s][4], vals[s][5]),
                                     pk2(vals[s][6], vals[s][7]));
                *(uint4*)(A + (s * 16 + nn) * 136 + q * 32 + j4 * 8) = d;
            }
        }

        // ---- hidden layers 1..3: B-frags in regs, 8 u-tiles per wave ----
        #pragma unroll 1
        for (int l = 0; l < 3; l++) {
            const unsigned short* WpL = wsU + l * 32768;
            const float* bl = (l == 0) ? b1 : (l == 1) ? b2 : b3;
            FragU bf[4][4];
            #pragma unroll
            for (int s = 0; s < 4; s++)
                #pragma unroll
                for (int ks = 0; ks < 4; ks++)
                    bf[s][ks].q = *(const uint4*)(A + (s * 16 + nn) * 136 + ks * 32 + q * 8);
            #pragma unroll
            for (int ut = 0; ut < 8; ut++) {
                FragU wh[4];
                #pragma unroll
                for (int ks = 0; ks < 4; ks++)
                    wh[ks].q = *(const uint4*)(WpL + (((ut * 4 + ks) * 64 + lane) << 3));
                f32x4 acc[4];
                #pragma unroll
                for (int s = 0; s < 4; s++) {
                    acc[s][0] = 0.f; acc[s][1] = 0.f;
                    acc[s][2] = 0.f; acc[s][3] = 0.f;
                }
                #pragma unroll
                for (int ks = 0; ks < 4; ks++)
                    #pragma unroll
                    for (int s = 0; s < 4; s++)
                        acc[s] = __builtin_amdgcn_mfma_f32_16x16x32_f16(
                            wh[ks].b, bf[s][ks].b, acc[s], 0, 0, 0);
                F4 bv; bv.v = *(const float4*)(bl + ut * 16 + q * 4);
                float vals[4][4];
                #pragma unroll
                for (int r = 0; r < 4; r++) {
                    float z  = acc[0][r] + bv.f[r];
                    float zx = acc[1][r], zy = acc[2][r], zl = acc[3][r];
                    float tt = fast_tanh(z);
                    float s2 = 1.f - tt * tt;
                    float m2 = -2.f * tt * s2;
                    vals[0][r] = tt;
                    vals[1][r] = s2 * zx;
                    vals[2][r] = s2 * zy;
                    vals[3][r] = s2 * zl + m2 * (zx * zx + zy * zy);
                }
                #pragma unroll
                for (int s = 0; s < 4; s++) {
                    uint2 d = make_uint2(pk2(vals[s][0], vals[s][1]),
                                         pk2(vals[s][2], vals[s][3]));
                    *(uint2*)(A + (s * 16 + nn) * 136 + ut * 16 + q * 4) = d;
                }
            }
        }

        // ---- layer 4 (padded W4, hi+lo): outputs stay in registers ----
        f32x4 a4[4];
        #pragma unroll
        for (int s = 0; s < 4; s++) {
            a4[s][0] = 0.f; a4[s][1] = 0.f; a4[s][2] = 0.f; a4[s][3] = 0.f;
        }
        #pragma unroll
        for (int ks = 0; ks < 4; ks++) {
            FragU wh, wl;
            const unsigned short* base = wsU + 102400 + ((ks * 64 + lane) << 3);
            wh.q = *(const uint4*)base;
            wl.q = *(const uint4*)(base + 2048);
            #pragma unroll
            for (int s = 0; s < 4; s++) {
                FragU bh;
                bh.q = *(const uint4*)(A + (s * 16 + nn) * 136 + ks * 32 + q * 8);
                a4[s] = __builtin_amdgcn_mfma_f32_16x16x32_f16(wh.b, bh.b, a4[s], 0, 0, 0);
                a4[s] = __builtin_amdgcn_mfma_f32_16x16x32_f16(wl.b, bh.b, a4[s], 0, 0, 0);
            }
        }

        // ---- residual: lane-local on q==0 lanes (pt nn) ----
        float contrib = 0.f;
        if (q == 0) {
            float r  = a4[0][0] + b4[0], P = a4[0][1] + b4[1];
            float u  = a4[0][2] + b4[2], v = a4[0][3] + b4[3];
            float rx = a4[1][0], Px = a4[1][1], ux = a4[1][2], vx = a4[1][3];
            float ry = a4[2][0], Py = a4[2][1], uy = a4[2][2], vy = a4[2][3];
            float rl = a4[3][0], Pl = a4[3][1], ul = a4[3][2], vl = a4[3][3];
            const float GI = 2.5f;  // 1/(gamma-1)

            float q2 = u * u + v * v;
            float E  = P * GI + 0.5f * r * q2;
            float Ex = Px * GI + 0.5f * rx * q2 + r * (u * ux + v * vx);
            float Ey = Py * GI + 0.5f * ry * q2 + r * (u * uy + v * vy);
            float EpP = E + P;

            float f1x = rx * u + r * ux;
            float f2x = rx * u * u + 2.f * r * u * ux + Px;
            float f3x = rx * u * v + r * ux * v + r * u * vx;
            float f4x = ux * EpP + u * (Ex + Px);

            float g1y = ry * v + r * vy;
            float g2y = ry * u * v + r * uy * v + r * u * vy;
            float g3y = ry * v * v + 2.f * r * v * vy + Py;
            float g4y = vy * EpP + v * (Ey + Py);

            float qx  = 2.f * (u * ux + v * vx);
            float qy  = 2.f * (u * uy + v * vy);
            float ql  = 2.f * (ux * ux + uy * uy + vx * vx + vy * vy)
                      + 2.f * (u * ul + v * vl);

            float U1s = rl;
            float U2s = rl * u + 2.f * (rx * ux + ry * uy) + r * ul;
            float U3s = rl * v + 2.f * (rx * vx + ry * vy) + r * vl;
            float U4s = Pl * GI
                      + 0.5f * (rl * q2 + 2.f * (rx * qx + ry * qy) + r * ql);

            float r1 = f1x + g1y - mu * U1s;
            float r2 = f2x + g2y - mu * U2s;
            float r3 = f3x + g3y - mu * U3s;
            float r4 = f4x + g4y - mu * U4s;

            contrib = (r1 * r1 + r2 * r2 + r3 * r3 + r4 * r4 + 0.1f * mu * mu)
                      * (1.0f / (float)NTRAIN);
        }
        contrib += __shfl_down(contrib, 32);
        contrib += __shfl_down(contrib, 16);
        contrib += __shfl_down(contrib, 8);
        contrib += __shfl_down(contrib, 4);
        contrib += __shfl_down(contrib, 2);
        contrib += __shfl_down(contrib, 1);
        if (lane == 0) atomicAdd(out, contrib);
    } else {
        // =================== BOUNDARY (64 pts per wave) ===================
        const int wj    = blockIdx.x - PHYS_WPROB;   // 0..255
        const int batch = wj >> 6;                   // 0..3
        const int lb    = wj & 63;
        const float* xs = (batch == 0) ? x_inlet
                        : (batch == 1) ? x_base
                        : (batch == 2) ? x_top : x_slip;
        const int base_pt = lb * 64;

        // ---- layer 0: rows rt*16+nn (rt = pt-tile), units q*32.. ----
        #pragma unroll 1
        for (int g2 = 0; g2 < 4; g2++) {
            const float2 xy = *(const float2*)(xs + (base_pt + g2 * 16 + nn) * 2);
            #pragma unroll
            for (int j4 = 0; j4 < 4; j4++) {
                float tv[8];
                #pragma unroll
                for (int j = 0; j < 8; j++) {
                    int u = q * 32 + j4 * 8 + j;
                    tv[j] = fast_tanh(xy.x * W0[u] + xy.y * W0[128 + u] + b0[u]);
                }
                uint4 d = make_uint4(pk2(tv[0], tv[1]), pk2(tv[2], tv[3]),
                                     pk2(tv[4], tv[5]), pk2(tv[6], tv[7]));
                *(uint4*)(A + (g2 * 16 + nn) * 136 + q * 32 + j4 * 8) = d;
            }
        }

        // ---- hidden layers 1..3 (tanh-only epilogue) ----
        #pragma unroll 1
        for (int l = 0; l < 3; l++) {
            const unsigned short* WpL = wsU + l * 32768;
            const float* bl = (l == 0) ? b1 : (l == 1) ? b2 : b3;
            FragU bf[4][4];
            #pragma unroll
            for (int rt = 0; rt < 4; rt++)
                #pragma unroll
                for (int ks = 0; ks < 4; ks++)
                    bf[rt][ks].q = *(const uint4*)(A + (rt * 16 + nn) * 136 + ks * 32 + q * 8);
            #pragma unroll
            for (int ut = 0; ut < 8; ut++) {
                FragU wh[4];
                #pragma unroll
                for (int ks = 0; ks < 4; ks++)
                    wh[ks].q = *(const uint4*)(WpL + (((ut * 4 + ks) * 64 + lane) << 3));
                f32x4 acc[4];
                #pragma unroll
                for (int rt = 0; rt < 4; rt++) {
                    acc[rt][0] = 0.f; acc[rt][1] = 0.f;
                    acc[rt][2] = 0.f; acc[rt][3] = 0.f;
                }
                #pragma unroll
                for (int ks = 0; ks < 4; ks++)
                    #pragma unroll
                    for (int rt = 0; rt < 4; rt++)
                        acc[rt] = __builtin_amdgcn_mfma_f32_16x16x32_f16(
                            wh[ks].b, bf[rt][ks].b, acc[rt], 0, 0, 0);
                F4 bv; bv.v = *(const float4*)(bl + ut * 16 + q * 4);
                #pragma unroll
                for (int rt = 0; rt < 4; rt++) {
                    float t0 = fast_tanh(acc[rt][0] + bv.f[0]);
                    float t1 = fast_tanh(acc[rt][1] + bv.f[1]);
                    float t2 = fast_tanh(acc[rt][2] + bv.f[2]);
                    float t3 = fast_tanh(acc[rt][3] + bv.f[3]);
                    uint2 d = make_uint2(pk2(t0, t1), pk2(t2, t3));
                    *(uint2*)(A + (rt * 16 + nn) * 136 + ut * 16 + q * 4) = d;
                }
            }
        }

        // ---- layer 4 (padded W4, hi+lo) ----
        f32x4 a4[4];
        #pragma unroll
        for (int rt = 0; rt < 4; rt++) {
            a4[rt][0] = 0.f; a4[rt][1] = 0.f; a4[rt][2] = 0.f; a4[rt][3] = 0.f;
        }
        #pragma unroll
        for (int ks = 0; ks < 4; ks++) {
            FragU wh, wl;
            const unsigned short* base = wsU + 102400 + ((ks * 64 + lane) << 3);
            wh.q = *(const uint4*)base;
            wl.q = *(const uint4*)(base + 2048);
            #pragma unroll
            for (int rt = 0; rt < 4; rt++) {
                FragU bh;
                bh.q = *(const uint4*)(A + (rt * 16 + nn) * 136 + ks * 32 + q * 8);
                a4[rt] = __builtin_amdgcn_mfma_f32_16x16x32_f16(wh.b, bh.b, a4[rt], 0, 0, 0);
                a4[rt] = __builtin_amdgcn_mfma_f32_16x16x32_f16(wl.b, bh.b, a4[rt], 0, 0, 0);
            }
        }

        // ---- loss: q==0 lanes handle 4 pts each (one per rt) ----
        float contrib = 0.f;
        if (q == 0) {
            #pragma unroll
            for (int rt = 0; rt < 4; rt++) {
                float o0 = a4[rt][0] + b4[0], o1 = a4[rt][1] + b4[1];
                float o2 = a4[rt][2] + b4[2], o3 = a4[rt][3] + b4[3];
                float lv;
                if (batch == 0) {
                    float4 Ui = *(const float4*)(U_inlet + (base_pt + rt * 16 + nn) * 4);
                    float d0 = o0 - Ui.x, d1 = o1 - Ui.y, d2 = o2 - Ui.z, d3 = o3 - Ui.w;
                    lv = d0 * d0 + d1 * d1 + d2 * d2 + d3 * d3;
                } else if (batch == 3) {
                    const float sa = -0.17364817766693033f;  // sin(-pi/18)
                    const float ca =  0.9848077530122080f;   // cos(-pi/18)
                    float d = -o2 * sa + o3 * ca;
                    lv = d * d;
                } else {
                    lv = o3 * o3;
                }
                contrib += 10.0f * lv * (1.0f / (float)NBDY);
            }
        }
        contrib += __shfl_down(contrib, 32);
        contrib += __shfl_down(contrib, 16);
        contrib += __shfl_down(contrib, 8);
        contrib += __shfl_down(contrib, 4);
        contrib += __shfl_down(contrib, 2);
        contrib += __shfl_down(contrib, 1);
        if (lane == 0) atomicAdd(out, contrib);
    }
}

extern "C" void kernel_launch(void* const* d_in, const int* in_sizes, int n_in,
                              void* d_out, int out_size, void* d_ws, size_t ws_size,
                              hipStream_t stream) {
    const float* xt      = (const float*)d_in[0];
    const float* x_inlet = (const float*)d_in[1];
    const float* U_inlet = (const float*)d_in[2];
    const float* x_base  = (const float*)d_in[3];
    const float* x_top   = (const float*)d_in[4];
    const float* x_slip  = (const float*)d_in[5];
    const float* W0 = (const float*)d_in[6];
    const float* b0 = (const float*)d_in[7];
    const float* W1 = (const float*)d_in[8];
    const float* b1 = (const float*)d_in[9];
    const float* W2 = (const float*)d_in[10];
    const float* b2 = (const float*)d_in[11];
    const float* W3 = (const float*)d_in[12];
    const float* b3 = (const float*)d_in[13];
    const float* W4 = (const float*)d_in[14];
    const float* b4 = (const float*)d_in[15];
    const float* V0 = (const float*)d_in[16];
    const float* c0 = (const float*)d_in[17];
    const float* V1 = (const float*)d_in[18];
    const float* c1 = (const float*)d_in[19];
    const float* V2 = (const float*)d_in[20];
    const float* c2 = (const float*)d_in[21];
    float* out = (float*)d_out;
    unsigned short* wsU = (unsigned short*)d_ws;

    pack_w_kernel<<<26, 256, 0, stream>>>(W1, W2, W3, V1, W4, wsU, out);

    fused_kernel<<<PHYS_WPROB + BDY_WPROB, 64, LDS_BYTES, stream>>>(
        xt, x_inlet, U_inlet, x_base, x_top, x_slip,
        W0, b0, W1, b1, W2, b2, W3, b3, W4, b4,
        V0, c0, V1, c1, V2, c2, wsU, out);
}

// Round 5
// 146.719 us; speedup vs baseline: 1.0640x; 1.0640x over previous
//
#include <hip/hip_runtime.h>

#define NTRAIN 32768
#define NBDY   4096
#define NBLK   1024   // 1024 blocks: 32 phys pts + 16 bdy pts each. 4/CU, 1 round.

typedef _Float16 f16x8 __attribute__((ext_vector_type(8)));
typedef __fp16   fp16x2 __attribute__((ext_vector_type(2)));
typedef float    f32x4 __attribute__((ext_vector_type(4)));

union FragU { uint4 q; f16x8 b; _Float16 e[8]; };
union F4  { float4 v; float f[4]; };
union H2  { fp16x2 h; _Float16 e[2]; unsigned int u; };

__device__ __forceinline__ float fast_tanh(float z) {
    float e = __expf(2.0f * z);
    return 1.0f - 2.0f * __builtin_amdgcn_rcpf(e + 1.0f);
}

__device__ __forceinline__ unsigned int pk2(float a, float b) {
    H2 r; r.h = __builtin_amdgcn_cvt_pkrtz(a, b);
    return r.u;
}

// ---------------------------------------------------------------------------
// Pack weights into MFMA A-fragment order (fp16 hi+lo).  (unchanged)
// W1..W3: hi at wsU + l*32768, lo at +16384 (lo unused by fused hidden layers).
// V1-hi at wsU+98304. W4 padded 128x16: hi at wsU+102400, lo +2048.
// Block 24 zeroes out[0].
// ---------------------------------------------------------------------------
__global__ __launch_bounds__(256) void pack_w_kernel(
    const float* __restrict__ W1, const float* __restrict__ W2,
    const float* __restrict__ W3, const float* __restrict__ V1,
    const float* __restrict__ W4,
    unsigned short* __restrict__ wsU, float* __restrict__ out)
{
    int b = blockIdx.x;
    if (b < 24) {
        int mat = b >> 3, rb = b & 7;          // 16 rows per block
        const float* W = (mat == 0) ? W1 : (mat == 1) ? W2 : W3;
        unsigned int* hiU = (unsigned int*)(wsU + mat * 32768);
        unsigned int* loU = hiU + 8192;
        int n   = threadIdx.x & 127;
        int pr0 = threadIdx.x >> 7;
        #pragma unroll
        for (int it = 0; it < 4; it++) {
            int pr = pr0 + 2 * it;
            int k  = rb * 16 + pr * 2;
            float v0 = W[k * 128 + n];
            float v1 = W[(k + 1) * 128 + n];
            H2 hh, ll;
            hh.e[0] = (_Float16)v0;
            hh.e[1] = (_Float16)v1;
            ll.e[0] = (_Float16)(v0 - (float)hh.e[0]);
            ll.e[1] = (_Float16)(v1 - (float)hh.e[1]);
            int base = ((n >> 4) * 4 + (k >> 5)) * 64 + ((k >> 3) & 3) * 16 + (n & 15);
            int uoff = base * 4 + ((k & 7) >> 1);
            hiU[uoff] = hh.u;
            loU[uoff] = ll.u;
        }
    } else if (b == 24) {
        unsigned int* hiU = (unsigned int*)(wsU + 98304);
        int n   = threadIdx.x & 63;
        int pr0 = threadIdx.x >> 6;
        #pragma unroll
        for (int it = 0; it < 8; it++) {
            int pr = pr0 + 4 * it;
            int k  = pr * 2;
            float v0 = V1[k * 64 + n];
            float v1 = V1[(k + 1) * 64 + n];
            H2 hh;
            hh.e[0] = (_Float16)v0;
            hh.e[1] = (_Float16)v1;
            int base = ((n >> 4) * 2 + (k >> 5)) * 64 + ((k >> 3) & 3) * 16 + (n & 15);
            hiU[base * 4 + ((k & 7) >> 1)] = hh.u;
        }
        if (threadIdx.x == 0) out[0] = 0.f;
    } else {
        _Float16* hi = (_Float16*)(wsU + 102400);
        _Float16* lo = hi + 2048;
        int u4 = threadIdx.x;
        int lane = u4 & 63, ks = u4 >> 6;
        int m  = lane & 15;
        int kb = ks * 32 + ((lane >> 4) << 3);
        FragU fh, fl;
        #pragma unroll
        for (int j = 0; j < 8; j++) {
            float v = (m < 4) ? W4[(kb + j) * 4 + m] : 0.f;
            _Float16 h = (_Float16)v;
            fh.e[j] = h;
            fl.e[j] = (_Float16)(v - (float)h);
        }
        *(uint4*)(hi + u4 * 8) = fh.q;
        *(uint4*)(lo + u4 * 8) = fl.q;
    }
}

// ---------------------------------------------------------------------------
// Fused kernel, r22 = r18 (champion, 32-pt/256-thr) + boundary folded in as a
// 9th row-tile. Every block: 32 phys pts (8 AD row-tiles) + 16 bdy pts (1
// value-only row-tile) through the SAME hidden-layer loop and barriers.
// Grid = exactly 1024 uniform blocks = 256 CU x 4 resident -> one clean
// round, no partial-round tail, no phys/bdy imbalance.
// LDS 39,424 B static (A-tile 144x136 ushorts, OUTF in 16B row pads, MUPART).
// BIASF dropped: epilogue reads b1/b2/b3 from L1 directly.
// ---------------------------------------------------------------------------
__global__ __launch_bounds__(256, 4) void fused_kernel(
    const float* __restrict__ xt,
    const float* __restrict__ x_inlet, const float* __restrict__ U_inlet,
    const float* __restrict__ x_base,  const float* __restrict__ x_top,
    const float* __restrict__ x_slip,
    const float* __restrict__ W0, const float* __restrict__ b0,
    const float* __restrict__ W1, const float* __restrict__ b1,
    const float* __restrict__ W2, const float* __restrict__ b2,
    const float* __restrict__ W3, const float* __restrict__ b3,
    const float* __restrict__ W4, const float* __restrict__ b4,
    const float* __restrict__ V0, const float* __restrict__ c0,
    const float* __restrict__ V1, const float* __restrict__ c1,
    const float* __restrict__ V2, const float* __restrict__ c2,
    const unsigned short* __restrict__ wsU,
    float* __restrict__ out)
{
    __shared__ float SM[9856];   // 39,424 B
    unsigned short* AhU = (unsigned short*)SM;   // 144 rows x 136 ushorts
    float* MUPART = SM + 9792;                   // 64 floats
    // OUTF(r): float4 in row r's 16B pad: bytes r*272 + 256 .. +271
    #define OUTF4(r) ((float4*)((char*)SM + (r) * 272 + 256))

    const int t = threadIdx.x;
    const int wv   = t >> 6;
    const int lane = t & 63;
    const int nn   = lane & 15;
    const int q    = lane >> 4;

    const int blk   = blockIdx.x;
    const int batch = blk >> 8;          // 0..3: inlet|base|top|slip
    const int bbase = (blk & 255) * 16;  // this block's 16 bdy points
    const float* xs = (batch == 0) ? x_inlet
                    : (batch == 1) ? x_base
                    : (batch == 2) ? x_top : x_slip;

    // ---- mu net: wave wv -> point-group g = wv>>1, unit-half h = wv&1 ----
    {
        const int g = wv >> 1, h = wv & 1;
        const float2 xyn = *(const float2*)(xt + (blk * 32 + g * 16 + nn) * 2);
        FragU mb[2];
        #pragma unroll
        for (int ks = 0; ks < 2; ks++) {
            int u0 = ks * 32 + q * 8;
            F4 va0, va1, vb0, vb1, cc0, cc1;
            va0.v = *(const float4*)(V0 + u0);
            va1.v = *(const float4*)(V0 + u0 + 4);
            vb0.v = *(const float4*)(V0 + 64 + u0);
            vb1.v = *(const float4*)(V0 + 64 + u0 + 4);
            cc0.v = *(const float4*)(c0 + u0);
            cc1.v = *(const float4*)(c0 + u0 + 4);
            #pragma unroll
            for (int i = 0; i < 4; i++) {
                mb[ks].e[i]     = (_Float16)fast_tanh(
                    xyn.x * va0.f[i] + xyn.y * vb0.f[i] + cc0.f[i]);
                mb[ks].e[4 + i] = (_Float16)fast_tanh(
                    xyn.x * va1.f[i] + xyn.y * vb1.f[i] + cc1.f[i]);
            }
        }
        float partial = 0.f;
        #pragma unroll
        for (int i = 0; i < 2; i++) {
            f32x4 macc = {0.f, 0.f, 0.f, 0.f};
            #pragma unroll
            for (int ks = 0; ks < 2; ks++) {
                FragU vh;
                vh.q = *(const uint4*)(wsU + 98304 +
                       ((((2 * h + i) * 2 + ks) * 64 + lane) << 3));
                macc = __builtin_amdgcn_mfma_f32_16x16x32_f16(vh.b, mb[ks].b, macc, 0, 0, 0);
            }
            int u2 = (2 * h + i) * 16 + q * 4;
            F4 cv, w2;
            cv.v = *(const float4*)(c1 + u2);
            w2.v = *(const float4*)(V2 + u2);
            #pragma unroll
            for (int r = 0; r < 4; r++)
                partial += fast_tanh(macc[r] + cv.f[r]) * w2.f[r];
        }
        partial += __shfl_xor(partial, 16);
        partial += __shfl_xor(partial, 32);
        if (lane < 16) MUPART[wv * 16 + nn] = partial;
    }

    {   // ---- phys layer 0: 2 -> 128, 4 streams, 2 points per thread ----
        const int pl = t >> 4, c = t & 15;
        #pragma unroll
        for (int h2 = 0; h2 < 2; h2++) {
            const int p = h2 * 16 + pl;
            const float2 xy = *(const float2*)(xt + (blk * 32 + p) * 2);
            const float x = xy.x, y = xy.y;
            float vals[4][8];
            #pragma unroll
            for (int j = 0; j < 8; j++) {
                int u = c * 8 + j;
                float w0 = W0[u], w1 = W0[128 + u];
                float zv = x * w0 + y * w1 + b0[u];
                float tt = fast_tanh(zv);
                float s2 = 1.f - tt * tt;
                float m2 = -2.f * tt * s2;
                vals[0][j] = tt;
                vals[1][j] = s2 * w0;
                vals[2][j] = s2 * w1;
                vals[3][j] = m2 * (w0 * w0 + w1 * w1);  // z_lap = 0 at layer 0
            }
            #pragma unroll
            for (int s = 0; s < 4; s++) {
                uint4 d = make_uint4(pk2(vals[s][0], vals[s][1]),
                                     pk2(vals[s][2], vals[s][3]),
                                     pk2(vals[s][4], vals[s][5]),
                                     pk2(vals[s][6], vals[s][7]));
                *(uint4*)(AhU + ((h2 * 4 + s) * 16 + pl) * 136 + c * 8) = d;
            }
        }
    }
    {   // ---- bdy layer 0: 16 pts, tanh only -> row-tile 8 (rows 128..143) --
        const int pl = t >> 4, c = t & 15;
        const float2 xy = *(const float2*)(xs + (bbase + pl) * 2);
        float tv[8];
        #pragma unroll
        for (int j = 0; j < 8; j++) {
            int u = c * 8 + j;
            tv[j] = fast_tanh(xy.x * W0[u] + xy.y * W0[128 + u] + b0[u]);
        }
        uint4 d = make_uint4(pk2(tv[0], tv[1]), pk2(tv[2], tv[3]),
                             pk2(tv[4], tv[5]), pk2(tv[6], tv[7]));
        *(uint4*)(AhU + (128 + pl) * 136 + c * 8) = d;
    }
    __syncthreads();

    // ---- hidden layers 1..3: 9 row-tiles, wave = 2 unit-tiles x 9 tiles ---
    #pragma unroll 1
    for (int l = 0; l < 3; l++) {
        const unsigned short* WpL = wsU + l * 32768;
        const float* bl = (l == 0) ? b1 : (l == 1) ? b2 : b3;
        f32x4 acc[2][9];
        #pragma unroll
        for (int i = 0; i < 2; i++)
            #pragma unroll
            for (int s = 0; s < 9; s++) {
                acc[i][s][0] = 0.f; acc[i][s][1] = 0.f;
                acc[i][s][2] = 0.f; acc[i][s][3] = 0.f;
            }
        #pragma unroll
        for (int ks = 0; ks < 4; ks++) {
            FragU wh[2];
            #pragma unroll
            for (int i = 0; i < 2; i++)
                wh[i].q = *(const uint4*)(WpL + ((((2 * wv + i) * 4 + ks) * 64 + lane) << 3));
            #pragma unroll
            for (int s = 0; s < 9; s++) {
                FragU bh;
                bh.q = *(const uint4*)(AhU + (s * 16 + nn) * 136 + ks * 32 + q * 8);
                acc[0][s] = __builtin_amdgcn_mfma_f32_16x16x32_f16(
                    wh[0].b, bh.b, acc[0][s], 0, 0, 0);
                acc[1][s] = __builtin_amdgcn_mfma_f32_16x16x32_f16(
                    wh[1].b, bh.b, acc[1][s], 0, 0, 0);
            }
        }
        __syncthreads();   // all A reads done before overwrite
        #pragma unroll
        for (int i = 0; i < 2; i++) {
            const int ubase = (2 * wv + i) * 16 + q * 4;
            F4 bv; bv.v = *(const float4*)(bl + ubase);
            #pragma unroll
            for (int g = 0; g < 2; g++) {   // phys point-groups
                float vals[4][4];
                #pragma unroll
                for (int r = 0; r < 4; r++) {
                    float z  = acc[i][g * 4 + 0][r] + bv.f[r];
                    float zx = acc[i][g * 4 + 1][r];
                    float zy = acc[i][g * 4 + 2][r];
                    float zl = acc[i][g * 4 + 3][r];
                    float tt = fast_tanh(z);
                    float s2 = 1.f - tt * tt;
                    float m2 = -2.f * tt * s2;
                    vals[0][r] = tt;
                    vals[1][r] = s2 * zx;
                    vals[2][r] = s2 * zy;
                    vals[3][r] = s2 * zl + m2 * (zx * zx + zy * zy);
                }
                #pragma unroll
                for (int s = 0; s < 4; s++) {
                    uint2 d = make_uint2(pk2(vals[s][0], vals[s][1]),
                                         pk2(vals[s][2], vals[s][3]));
                    *(uint2*)(AhU + ((g * 4 + s) * 16 + nn) * 136 + ubase) = d;
                }
            }
            {   // bdy tile: tanh only
                float t0 = fast_tanh(acc[i][8][0] + bv.f[0]);
                float t1 = fast_tanh(acc[i][8][1] + bv.f[1]);
                float t2 = fast_tanh(acc[i][8][2] + bv.f[2]);
                float t3 = fast_tanh(acc[i][8][3] + bv.f[3]);
                uint2 d = make_uint2(pk2(t0, t1), pk2(t2, t3));
                *(uint2*)(AhU + (128 + nn) * 136 + ubase) = d;
            }
        }
        __syncthreads();
    }

    // ---- layer 4: 128 -> 4 via MFMA (padded W4, hi+lo); 9 tiles/4 waves ---
    {
        const unsigned short* W4p = wsU + 102400;
        const int rtA = wv, rtB = 4 + wv;
        f32x4 aA = {0.f, 0.f, 0.f, 0.f};
        f32x4 aB = {0.f, 0.f, 0.f, 0.f};
        f32x4 aC = {0.f, 0.f, 0.f, 0.f};
        #pragma unroll
        for (int ks = 0; ks < 4; ks++) {
            FragU wh, wl, bA, bB;
            const unsigned short* base = W4p + ((ks * 64 + lane) << 3);
            wh.q = *(const uint4*)base;
            wl.q = *(const uint4*)(base + 2048);
            bA.q = *(const uint4*)(AhU + (rtA * 16 + nn) * 136 + ks * 32 + q * 8);
            bB.q = *(const uint4*)(AhU + (rtB * 16 + nn) * 136 + ks * 32 + q * 8);
            aA = __builtin_amdgcn_mfma_f32_16x16x32_f16(wh.b, bA.b, aA, 0, 0, 0);
            aA = __builtin_amdgcn_mfma_f32_16x16x32_f16(wl.b, bA.b, aA, 0, 0, 0);
            aB = __builtin_amdgcn_mfma_f32_16x16x32_f16(wh.b, bB.b, aB, 0, 0, 0);
            aB = __builtin_amdgcn_mfma_f32_16x16x32_f16(wl.b, bB.b, aB, 0, 0, 0);
            if (wv == 3) {   // wave 3 also handles the bdy tile (rt = 8)
                FragU bC;
                bC.q = *(const uint4*)(AhU + (128 + nn) * 136 + ks * 32 + q * 8);
                aC = __builtin_amdgcn_mfma_f32_16x16x32_f16(wh.b, bC.b, aC, 0, 0, 0);
                aC = __builtin_amdgcn_mfma_f32_16x16x32_f16(wl.b, bC.b, aC, 0, 0, 0);
            }
        }
        if (q == 0) {
            float4 oA = make_float4(aA[0], aA[1], aA[2], aA[3]);
            float4 oB = make_float4(aB[0], aB[1], aB[2], aB[3]);
            if (wv == 0) {   // rtA==0 and rtB==4 are the value streams
                oA.x += b4[0]; oA.y += b4[1]; oA.z += b4[2]; oA.w += b4[3];
                oB.x += b4[0]; oB.y += b4[1]; oB.z += b4[2]; oB.w += b4[3];
            }
            *OUTF4(rtA * 16 + nn) = oA;
            *OUTF4(rtB * 16 + nn) = oB;
            if (wv == 3) {
                float4 oC = make_float4(aC[0] + b4[0], aC[1] + b4[1],
                                        aC[2] + b4[2], aC[3] + b4[3]);
                *OUTF4(128 + nn) = oC;
            }
        }
    }
    __syncthreads();

    // ---- residual (phys, t<32) + bdy loss (wave 3 lanes 0..15) ------------
    float contrib = 0.f;
    if (t < 32) {
        const int pp = t, g = pp >> 4, p15 = pp & 15;
        F4 V, DX, DY, LAP;
        V.v   = *OUTF4((g * 4 + 0) * 16 + p15);
        DX.v  = *OUTF4((g * 4 + 1) * 16 + p15);
        DY.v  = *OUTF4((g * 4 + 2) * 16 + p15);
        LAP.v = *OUTF4((g * 4 + 3) * 16 + p15);
        float r = V.f[0],  P = V.f[1],  u = V.f[2],  v = V.f[3];
        float rx = DX.f[0], Px = DX.f[1], ux = DX.f[2], vx = DX.f[3];
        float ry = DY.f[0], Py = DY.f[1], uy = DY.f[2], vy = DY.f[3];
        float rl = LAP.f[0], Pl = LAP.f[1], ul = LAP.f[2], vl = LAP.f[3];
        const float GI = 2.5f;  // 1/(gamma-1)

        float s = MUPART[(2 * g) * 16 + p15] + MUPART[(2 * g + 1) * 16 + p15]
                + c2[0];
        float mu = 0.01f * s * s;

        float q2 = u * u + v * v;
        float E  = P * GI + 0.5f * r * q2;
        float Ex = Px * GI + 0.5f * rx * q2 + r * (u * ux + v * vx);
        float Ey = Py * GI + 0.5f * ry * q2 + r * (u * uy + v * vy);
        float EpP = E + P;

        float f1x = rx * u + r * ux;
        float f2x = rx * u * u + 2.f * r * u * ux + Px;
        float f3x = rx * u * v + r * ux * v + r * u * vx;
        float f4x = ux * EpP + u * (Ex + Px);

        float g1y = ry * v + r * vy;
        float g2y = ry * u * v + r * uy * v + r * u * vy;
        float g3y = ry * v * v + 2.f * r * v * vy + Py;
        float g4y = vy * EpP + v * (Ey + Py);

        float qx  = 2.f * (u * ux + v * vx);
        float qy  = 2.f * (u * uy + v * vy);
        float ql  = 2.f * (ux * ux + uy * uy + vx * vx + vy * vy)
                  + 2.f * (u * ul + v * vl);

        float U1s = rl;
        float U2s = rl * u + 2.f * (rx * ux + ry * uy) + r * ul;
        float U3s = rl * v + 2.f * (rx * vx + ry * vy) + r * vl;
        float U4s = Pl * GI
                  + 0.5f * (rl * q2 + 2.f * (rx * qx + ry * qy) + r * ql);

        float r1 = f1x + g1y - mu * U1s;
        float r2 = f2x + g2y - mu * U2s;
        float r3 = f3x + g3y - mu * U3s;
        float r4 = f4x + g4y - mu * U4s;

        contrib = (r1 * r1 + r2 * r2 + r3 * r3 + r4 * r4 + 0.1f * mu * mu)
                  * (1.0f / (float)NTRAIN);
    } else if (t >= 192 && t < 208) {
        const int pb = t - 192;   // bdy point 0..15
        F4 O; O.v = *OUTF4(128 + pb);
        float o0 = O.f[0], o1 = O.f[1], o2 = O.f[2], o3 = O.f[3];
        float lv;
        if (batch == 0) {
            float4 Ui = *(const float4*)(U_inlet + (bbase + pb) * 4);
            float d0 = o0 - Ui.x, d1 = o1 - Ui.y, d2 = o2 - Ui.z, d3 = o3 - Ui.w;
            lv = d0 * d0 + d1 * d1 + d2 * d2 + d3 * d3;
        } else if (batch == 3) {
            const float sa = -0.17364817766693033f;  // sin(-pi/18)
            const float ca =  0.9848077530122080f;   // cos(-pi/18)
            float d = -o2 * sa + o3 * ca;
            lv = d * d;
        } else {
            lv = o3 * o3;
        }
        contrib = 10.0f * lv * (1.0f / (float)NBDY);
    }
    if (wv == 0 || wv == 3) {
        contrib += __shfl_down(contrib, 32);
        contrib += __shfl_down(contrib, 16);
        contrib += __shfl_down(contrib, 8);
        contrib += __shfl_down(contrib, 4);
        contrib += __shfl_down(contrib, 2);
        contrib += __shfl_down(contrib, 1);
        if (lane == 0) atomicAdd(out, contrib);
    }
    #undef OUTF4
}

extern "C" void kernel_launch(void* const* d_in, const int* in_sizes, int n_in,
                              void* d_out, int out_size, void* d_ws, size_t ws_size,
                              hipStream_t stream) {
    const float* xt      = (const float*)d_in[0];
    const float* x_inlet = (const float*)d_in[1];
    const float* U_inlet = (const float*)d_in[2];
    const float* x_base  = (const float*)d_in[3];
    const float* x_top   = (const float*)d_in[4];
    const float* x_slip  = (const float*)d_in[5];
    const float* W0 = (const float*)d_in[6];
    const float* b0 = (const float*)d_in[7];
    const float* W1 = (const float*)d_in[8];
    const float* b1 = (const float*)d_in[9];
    const float* W2 = (const float*)d_in[10];
    const float* b2 = (const float*)d_in[11];
    const float* W3 = (const float*)d_in[12];
    const float* b3 = (const float*)d_in[13];
    const float* W4 = (const float*)d_in[14];
    const float* b4 = (const float*)d_in[15];
    const float* V0 = (const float*)d_in[16];
    const float* c0 = (const float*)d_in[17];
    const float* V1 = (const float*)d_in[18];
    const float* c1 = (const float*)d_in[19];
    const float* V2 = (const float*)d_in[20];
    const float* c2 = (const float*)d_in[21];
    float* out = (float*)d_out;
    unsigned short* wsU = (unsigned short*)d_ws;

    pack_w_kernel<<<26, 256, 0, stream>>>(W1, W2, W3, V1, W4, wsU, out);

    fused_kernel<<<NBLK, 256, 0, stream>>>(
        xt, x_inlet, U_inlet, x_base, x_top, x_slip,
        W0, b0, W1, b1, W2, b2, W3, b3, W4, b4,
        V0, c0, V1, c1, V2, c2, wsU, out);
}

// Round 6
// 128.851 us; speedup vs baseline: 1.2116x; 1.1387x over previous
//
#include <hip/hip_runtime.h>

#define NTRAIN 32768
#define NBDY   4096
#define PHYS_BLOCKS (NTRAIN / 32)   // 1024 blocks, 32 pts each
#define BDY_BLOCKS  256             // 64 pts/block, 64 blocks per batch

typedef _Float16 f16x8 __attribute__((ext_vector_type(8)));
typedef __fp16   fp16x2 __attribute__((ext_vector_type(2)));
typedef float    f32x4 __attribute__((ext_vector_type(4)));

union FragU { uint4 q; f16x8 b; _Float16 e[8]; };
union F4  { float4 v; float f[4]; };
union H2  { fp16x2 h; _Float16 e[2]; unsigned int u; };

__device__ __forceinline__ float fast_tanh(float z) {
    float e = __expf(2.0f * z);
    return 1.0f - 2.0f * __builtin_amdgcn_rcpf(e + 1.0f);
}

__device__ __forceinline__ unsigned int pk2(float a, float b) {
    H2 r; r.h = __builtin_amdgcn_cvt_pkrtz(a, b);
    return r.u;
}

// ---------------------------------------------------------------------------
// Pack weights into MFMA A-fragment order (fp16 hi+lo).  (unchanged)
// W1..W3: hi at wsU + l*32768, lo at +16384 (lo unused by fused hidden layers).
// V1-hi at wsU+98304. W4 padded 128x16: hi at wsU+102400, lo +2048.
// Block 24 zeroes out[0].
// ---------------------------------------------------------------------------
__global__ __launch_bounds__(256) void pack_w_kernel(
    const float* __restrict__ W1, const float* __restrict__ W2,
    const float* __restrict__ W3, const float* __restrict__ V1,
    const float* __restrict__ W4,
    unsigned short* __restrict__ wsU, float* __restrict__ out)
{
    int b = blockIdx.x;
    if (b < 24) {
        int mat = b >> 3, rb = b & 7;          // 16 rows per block
        const float* W = (mat == 0) ? W1 : (mat == 1) ? W2 : W3;
        unsigned int* hiU = (unsigned int*)(wsU + mat * 32768);
        unsigned int* loU = hiU + 8192;
        int n   = threadIdx.x & 127;
        int pr0 = threadIdx.x >> 7;
        #pragma unroll
        for (int it = 0; it < 4; it++) {
            int pr = pr0 + 2 * it;
            int k  = rb * 16 + pr * 2;
            float v0 = W[k * 128 + n];
            float v1 = W[(k + 1) * 128 + n];
            H2 hh, ll;
            hh.e[0] = (_Float16)v0;
            hh.e[1] = (_Float16)v1;
            ll.e[0] = (_Float16)(v0 - (float)hh.e[0]);
            ll.e[1] = (_Float16)(v1 - (float)hh.e[1]);
            int base = ((n >> 4) * 4 + (k >> 5)) * 64 + ((k >> 3) & 3) * 16 + (n & 15);
            int uoff = base * 4 + ((k & 7) >> 1);
            hiU[uoff] = hh.u;
            loU[uoff] = ll.u;
        }
    } else if (b == 24) {
        unsigned int* hiU = (unsigned int*)(wsU + 98304);
        int n   = threadIdx.x & 63;
        int pr0 = threadIdx.x >> 6;
        #pragma unroll
        for (int it = 0; it < 8; it++) {
            int pr = pr0 + 4 * it;
            int k  = pr * 2;
            float v0 = V1[k * 64 + n];
            float v1 = V1[(k + 1) * 64 + n];
            H2 hh;
            hh.e[0] = (_Float16)v0;
            hh.e[1] = (_Float16)v1;
            int base = ((n >> 4) * 2 + (k >> 5)) * 64 + ((k >> 3) & 3) * 16 + (n & 15);
            hiU[base * 4 + ((k & 7) >> 1)] = hh.u;
        }
        if (threadIdx.x == 0) out[0] = 0.f;
    } else {
        _Float16* hi = (_Float16*)(wsU + 102400);
        _Float16* lo = hi + 2048;
        int u4 = threadIdx.x;
        int lane = u4 & 63, ks = u4 >> 6;
        int m  = lane & 15;
        int kb = ks * 32 + ((lane >> 4) << 3);
        FragU fh, fl;
        #pragma unroll
        for (int j = 0; j < 8; j++) {
            float v = (m < 4) ? W4[(kb + j) * 4 + m] : 0.f;
            _Float16 h = (_Float16)v;
            fh.e[j] = h;
            fl.e[j] = (_Float16)(v - (float)h);
        }
        *(uint4*)(hi + u4 * 8) = fh.q;
        *(uint4*)(lo + u4 * 8) = fl.q;
    }
}

// ---------------------------------------------------------------------------
// Fused kernel, r23 = r18 champion (32-pt/256-thr, 38.9KB LDS) with two
// de-lockstep changes:
//  (1) hidden-layer epilogue VALU moved BEFORE barrier-1 (packed into uint2
//      regs); bar1->bar2 segment is now just the 16 ds_write_b64. A fast
//      wave's epilogue VALU overlaps slow waves' MFMA across the boundary.
//  (2) s_setprio(1) around MFMA K-loops (hidden + L4): scheduler prefers
//      MFMA-issuing waves over epilogue-VALU waves (phase diversity exists
//      across the 4 resident blocks/CU).
// Everything else byte-identical to r18.
// ---------------------------------------------------------------------------
__global__ __launch_bounds__(256, 4) void fused_kernel(
    const float* __restrict__ xt,
    const float* __restrict__ x_inlet, const float* __restrict__ U_inlet,
    const float* __restrict__ x_base,  const float* __restrict__ x_top,
    const float* __restrict__ x_slip,
    const float* __restrict__ W0, const float* __restrict__ b0,
    const float* __restrict__ W1, const float* __restrict__ b1,
    const float* __restrict__ W2, const float* __restrict__ b2,
    const float* __restrict__ W3, const float* __restrict__ b3,
    const float* __restrict__ W4, const float* __restrict__ b4,
    const float* __restrict__ V0, const float* __restrict__ c0,
    const float* __restrict__ V1, const float* __restrict__ c1,
    const float* __restrict__ V2, const float* __restrict__ c2,
    const unsigned short* __restrict__ wsU,
    float* __restrict__ out)
{
    __shared__ float SM[9664];   // 38,656 B
    const int t = threadIdx.x;
    const int wv   = t >> 6;
    const int lane = t & 63;
    const int nn   = lane & 15;
    const int q    = lane >> 4;

    if (blockIdx.x < PHYS_BLOCKS) {
        // =================== PHYSICS PATH (32 pts) ===================
        unsigned short* AhU = (unsigned short*)SM;   // 128 rows x 136 ushorts
        float* OUTF   = SM + 8704;   // 128 x 4
        float* MUPART = SM + 9216;   // 64
        float* BIASF  = SM + 9280;   // 384 floats

        const int blk = blockIdx.x;

        if (t < 128) {
            BIASF[t]       = b1[t];
            BIASF[128 + t] = b2[t];
            BIASF[256 + t] = b3[t];
        }

        // ---- mu net: wave wv -> point-group g = wv>>1, unit-half h = wv&1 --
        {
            const int g = wv >> 1, h = wv & 1;
            const float2 xyn = *(const float2*)(xt + (blk * 32 + g * 16 + nn) * 2);
            FragU mb[2];
            #pragma unroll
            for (int ks = 0; ks < 2; ks++) {
                int u0 = ks * 32 + q * 8;
                F4 va0, va1, vb0, vb1, cc0, cc1;
                va0.v = *(const float4*)(V0 + u0);
                va1.v = *(const float4*)(V0 + u0 + 4);
                vb0.v = *(const float4*)(V0 + 64 + u0);
                vb1.v = *(const float4*)(V0 + 64 + u0 + 4);
                cc0.v = *(const float4*)(c0 + u0);
                cc1.v = *(const float4*)(c0 + u0 + 4);
                #pragma unroll
                for (int i = 0; i < 4; i++) {
                    mb[ks].e[i]     = (_Float16)fast_tanh(
                        xyn.x * va0.f[i] + xyn.y * vb0.f[i] + cc0.f[i]);
                    mb[ks].e[4 + i] = (_Float16)fast_tanh(
                        xyn.x * va1.f[i] + xyn.y * vb1.f[i] + cc1.f[i]);
                }
            }
            float partial = 0.f;
            #pragma unroll
            for (int i = 0; i < 2; i++) {
                f32x4 macc = {0.f, 0.f, 0.f, 0.f};
                #pragma unroll
                for (int ks = 0; ks < 2; ks++) {
                    FragU vh;
                    vh.q = *(const uint4*)(wsU + 98304 +
                           ((((2 * h + i) * 2 + ks) * 64 + lane) << 3));
                    macc = __builtin_amdgcn_mfma_f32_16x16x32_f16(vh.b, mb[ks].b, macc, 0, 0, 0);
                }
                int u2 = (2 * h + i) * 16 + q * 4;
                F4 cv, w2;
                cv.v = *(const float4*)(c1 + u2);
                w2.v = *(const float4*)(V2 + u2);
                #pragma unroll
                for (int r = 0; r < 4; r++)
                    partial += fast_tanh(macc[r] + cv.f[r]) * w2.f[r];
            }
            partial += __shfl_xor(partial, 16);
            partial += __shfl_xor(partial, 32);
            if (lane < 16) MUPART[wv * 16 + nn] = partial;
        }
        {   // main layer 0: 2 -> 128, 4 streams, 2 point-halves per thread
            const int pl = t >> 4, c = t & 15;
            #pragma unroll
            for (int h2 = 0; h2 < 2; h2++) {
                const int p = h2 * 16 + pl;
                const float2 xy = *(const float2*)(xt + (blk * 32 + p) * 2);
                const float x = xy.x, y = xy.y;
                float vals[4][8];
                #pragma unroll
                for (int j = 0; j < 8; j++) {
                    int u = c * 8 + j;
                    float w0 = W0[u], w1 = W0[128 + u];
                    float zv = x * w0 + y * w1 + b0[u];
                    float tt = fast_tanh(zv);
                    float s2 = 1.f - tt * tt;
                    float m2 = -2.f * tt * s2;
                    vals[0][j] = tt;
                    vals[1][j] = s2 * w0;
                    vals[2][j] = s2 * w1;
                    vals[3][j] = m2 * (w0 * w0 + w1 * w1);  // z_lap = 0 at layer 0
                }
                #pragma unroll
                for (int s = 0; s < 4; s++) {
                    uint4 d = make_uint4(pk2(vals[s][0], vals[s][1]),
                                         pk2(vals[s][2], vals[s][3]),
                                         pk2(vals[s][4], vals[s][5]),
                                         pk2(vals[s][6], vals[s][7]));
                    *(uint4*)(AhU + ((h2 * 4 + s) * 16 + pl) * 136 + c * 8) = d;
                }
            }
        }
        __syncthreads();

        // ------- hidden layers 1..3 via MFMA (8 row-tiles, W-hi 1-pass) ----
        #pragma unroll 1
        for (int l = 0; l < 3; l++) {
            const unsigned short* WpL = wsU + l * 32768;
            f32x4 acc[2][8];
            #pragma unroll
            for (int i = 0; i < 2; i++)
                #pragma unroll
                for (int s = 0; s < 8; s++) {
                    acc[i][s][0] = 0.f; acc[i][s][1] = 0.f;
                    acc[i][s][2] = 0.f; acc[i][s][3] = 0.f;
                }
            __builtin_amdgcn_s_setprio(1);
            #pragma unroll
            for (int ks = 0; ks < 4; ks++) {
                FragU wh[2];
                #pragma unroll
                for (int i = 0; i < 2; i++)
                    wh[i].q = *(const uint4*)(WpL + ((((2 * wv + i) * 4 + ks) * 64 + lane) << 3));
                #pragma unroll
                for (int s = 0; s < 8; s++) {
                    FragU bh;
                    bh.q = *(const uint4*)(AhU + (s * 16 + nn) * 136 + ks * 32 + q * 8);
                    acc[0][s] = __builtin_amdgcn_mfma_f32_16x16x32_f16(
                        wh[0].b, bh.b, acc[0][s], 0, 0, 0);
                    acc[1][s] = __builtin_amdgcn_mfma_f32_16x16x32_f16(
                        wh[1].b, bh.b, acc[1][s], 0, 0, 0);
                }
            }
            __builtin_amdgcn_s_setprio(0);
            // ---- epilogue VALU BEFORE barrier (registers only) ----
            uint2 pk[2][2][4];
            #pragma unroll
            for (int i = 0; i < 2; i++) {
                const int ubase = (2 * wv + i) * 16 + q * 4;
                F4 bv; bv.v = *(const float4*)&BIASF[l * 128 + ubase];
                #pragma unroll
                for (int g = 0; g < 2; g++) {
                    float vals[4][4];
                    #pragma unroll
                    for (int r = 0; r < 4; r++) {
                        float z  = acc[i][g * 4 + 0][r] + bv.f[r];
                        float zx = acc[i][g * 4 + 1][r];
                        float zy = acc[i][g * 4 + 2][r];
                        float zl = acc[i][g * 4 + 3][r];
                        float tt = fast_tanh(z);
                        float s2 = 1.f - tt * tt;
                        float m2 = -2.f * tt * s2;
                        vals[0][r] = tt;
                        vals[1][r] = s2 * zx;
                        vals[2][r] = s2 * zy;
                        vals[3][r] = s2 * zl + m2 * (zx * zx + zy * zy);
                    }
                    #pragma unroll
                    for (int s = 0; s < 4; s++)
                        pk[i][g][s] = make_uint2(pk2(vals[s][0], vals[s][1]),
                                                 pk2(vals[s][2], vals[s][3]));
                }
            }
            __syncthreads();   // all A reads done before overwrite
            #pragma unroll
            for (int i = 0; i < 2; i++) {
                const int ubase = (2 * wv + i) * 16 + q * 4;
                #pragma unroll
                for (int g = 0; g < 2; g++)
                    #pragma unroll
                    for (int s = 0; s < 4; s++)
                        *(uint2*)(AhU + ((g * 4 + s) * 16 + nn) * 136 + ubase) = pk[i][g][s];
            }
            __syncthreads();
        }

        // ---------------- layer 4: 128 -> 4 via MFMA (padded W4, hi+lo) ----
        {
            const unsigned short* W4p = wsU + 102400;
            const int rtA = wv, rtB = 4 + wv;
            f32x4 aA = {0.f, 0.f, 0.f, 0.f};
            f32x4 aB = {0.f, 0.f, 0.f, 0.f};
            __builtin_amdgcn_s_setprio(1);
            #pragma unroll
            for (int ks = 0; ks < 4; ks++) {
                FragU wh, wl, bA, bB;
                const unsigned short* base = W4p + ((ks * 64 + lane) << 3);
                wh.q = *(const uint4*)base;
                wl.q = *(const uint4*)(base + 2048);
                bA.q = *(const uint4*)(AhU + (rtA * 16 + nn) * 136 + ks * 32 + q * 8);
                bB.q = *(const uint4*)(AhU + (rtB * 16 + nn) * 136 + ks * 32 + q * 8);
                aA = __builtin_amdgcn_mfma_f32_16x16x32_f16(wh.b, bA.b, aA, 0, 0, 0);
                aA = __builtin_amdgcn_mfma_f32_16x16x32_f16(wl.b, bA.b, aA, 0, 0, 0);
                aB = __builtin_amdgcn_mfma_f32_16x16x32_f16(wh.b, bB.b, aB, 0, 0, 0);
                aB = __builtin_amdgcn_mfma_f32_16x16x32_f16(wl.b, bB.b, aB, 0, 0, 0);
            }
            __builtin_amdgcn_s_setprio(0);
            if (q == 0) {
                float4 oA = make_float4(aA[0], aA[1], aA[2], aA[3]);
                float4 oB = make_float4(aB[0], aB[1], aB[2], aB[3]);
                if (wv == 0) {   // rtA==0 / rtB==4 are the value streams
                    oA.x += b4[0]; oA.y += b4[1]; oA.z += b4[2]; oA.w += b4[3];
                    oB.x += b4[0]; oB.y += b4[1]; oB.z += b4[2]; oB.w += b4[3];
                }
                *(float4*)&OUTF[(rtA * 16 + nn) * 4] = oA;
                *(float4*)&OUTF[(rtB * 16 + nn) * 4] = oB;
            }
        }
        __syncthreads();

        // ---------------- per-point residual + reduction -------------------
        float contrib = 0.f;
        if (t < 32) {
            const int pp = t, g = pp >> 4, p15 = pp & 15;
            const float* V   = &OUTF[((g * 4 + 0) * 16 + p15) * 4];
            const float* DX  = &OUTF[((g * 4 + 1) * 16 + p15) * 4];
            const float* DY  = &OUTF[((g * 4 + 2) * 16 + p15) * 4];
            const float* LAP = &OUTF[((g * 4 + 3) * 16 + p15) * 4];
            float r = V[0],  P = V[1],  u = V[2],  v = V[3];
            float rx = DX[0], Px = DX[1], ux = DX[2], vx = DX[3];
            float ry = DY[0], Py = DY[1], uy = DY[2], vy = DY[3];
            float rl = LAP[0], Pl = LAP[1], ul = LAP[2], vl = LAP[3];
            const float GI = 2.5f;  // 1/(gamma-1)

            float s = MUPART[(2 * g) * 16 + p15] + MUPART[(2 * g + 1) * 16 + p15]
                    + c2[0];
            float mu = 0.01f * s * s;

            float q2 = u * u + v * v;
            float E  = P * GI + 0.5f * r * q2;
            float Ex = Px * GI + 0.5f * rx * q2 + r * (u * ux + v * vx);
            float Ey = Py * GI + 0.5f * ry * q2 + r * (u * uy + v * vy);
            float EpP = E + P;

            float f1x = rx * u + r * ux;
            float f2x = rx * u * u + 2.f * r * u * ux + Px;
            float f3x = rx * u * v + r * ux * v + r * u * vx;
            float f4x = ux * EpP + u * (Ex + Px);

            float g1y = ry * v + r * vy;
            float g2y = ry * u * v + r * uy * v + r * u * vy;
            float g3y = ry * v * v + 2.f * r * v * vy + Py;
            float g4y = vy * EpP + v * (Ey + Py);

            float qx  = 2.f * (u * ux + v * vx);
            float qy  = 2.f * (u * uy + v * vy);
            float ql  = 2.f * (ux * ux + uy * uy + vx * vx + vy * vy)
                      + 2.f * (u * ul + v * vl);

            float U1s = rl;
            float U2s = rl * u + 2.f * (rx * ux + ry * uy) + r * ul;
            float U3s = rl * v + 2.f * (rx * vx + ry * vy) + r * vl;
            float U4s = Pl * GI
                      + 0.5f * (rl * q2 + 2.f * (rx * qx + ry * qy) + r * ql);

            float r1 = f1x + g1y - mu * U1s;
            float r2 = f2x + g2y - mu * U2s;
            float r3 = f3x + g3y - mu * U3s;
            float r4 = f4x + g4y - mu * U4s;

            contrib = (r1 * r1 + r2 * r2 + r3 * r3 + r4 * r4 + 0.1f * mu * mu)
                      * (1.0f / (float)NTRAIN);
        }
        if (t < 64) {
            contrib += __shfl_down(contrib, 32);
            contrib += __shfl_down(contrib, 16);
            contrib += __shfl_down(contrib, 8);
            contrib += __shfl_down(contrib, 4);
            contrib += __shfl_down(contrib, 2);
            contrib += __shfl_down(contrib, 1);
            if (t == 0) atomicAdd(out, contrib);
        }
    } else {
        // =================== BOUNDARY PATH (MFMA, 64 pts/block) ============
        unsigned short* ShU = (unsigned short*)SM;   // 64 x 136
        float* OUTB  = SM + 4352;   // 64 x 4
        float* BIASB = SM + 4608;   // 384 floats

        const int bb    = blockIdx.x - PHYS_BLOCKS;
        const int batch = bb >> 6;  // 0..3 (64 blocks each)
        const int lb    = bb & 63;
        const float* xs = (batch == 0) ? x_inlet
                        : (batch == 1) ? x_base
                        : (batch == 2) ? x_top : x_slip;
        const int base_pt = lb * 64;

        // ---- layer 0: 2 -> 128 (4 threads/pt, 32 units each) + biases ----
        {
            int p2 = t & 63, ug = t >> 6;
            float2 xy = *(const float2*)(xs + (base_pt + p2) * 2);
            float x = xy.x, y = xy.y;
            #pragma unroll
            for (int g = 0; g < 8; g++) {
                int u0 = ug * 32 + g * 4;
                F4 wa, wb, bbv;
                wa.v  = *(const float4*)(W0 + u0);
                wb.v  = *(const float4*)(W0 + 128 + u0);
                bbv.v = *(const float4*)(b0 + u0);
                float t0 = fast_tanh(x * wa.f[0] + y * wb.f[0] + bbv.f[0]);
                float t1 = fast_tanh(x * wa.f[1] + y * wb.f[1] + bbv.f[1]);
                float t2 = fast_tanh(x * wa.f[2] + y * wb.f[2] + bbv.f[2]);
                float t3 = fast_tanh(x * wa.f[3] + y * wb.f[3] + bbv.f[3]);
                uint2 d = make_uint2(pk2(t0, t1), pk2(t2, t3));
                *(uint2*)(ShU + p2 * 136 + u0) = d;
            }
            if (t < 128) {
                BIASB[t]       = b1[t];
                BIASB[128 + t] = b2[t];
                BIASB[256 + t] = b3[t];
            }
        }
        __syncthreads();

        // ---- hidden layers 1..3 via MFMA (W hi only, 4 point-tiles) ----
        #pragma unroll 1
        for (int l = 0; l < 3; l++) {
            const unsigned short* WpL = wsU + l * 32768;
            f32x4 acc[2][4];
            #pragma unroll
            for (int i = 0; i < 2; i++)
                #pragma unroll
                for (int n = 0; n < 4; n++) {
                    acc[i][n][0] = 0.f; acc[i][n][1] = 0.f;
                    acc[i][n][2] = 0.f; acc[i][n][3] = 0.f;
                }
            __builtin_amdgcn_s_setprio(1);
            #pragma unroll
            for (int ks = 0; ks < 4; ks++) {
                FragU bh[4];
                #pragma unroll
                for (int n = 0; n < 4; n++)
                    bh[n].q = *(const uint4*)(ShU + (n * 16 + nn) * 136 + ks * 32 + q * 8);
                FragU wh[2];
                #pragma unroll
                for (int i = 0; i < 2; i++)
                    wh[i].q = *(const uint4*)(WpL + ((((2 * wv + i) * 4 + ks) * 64 + lane) << 3));
                #pragma unroll
                for (int i = 0; i < 2; i++)
                    #pragma unroll
                    for (int n = 0; n < 4; n++)
                        acc[i][n] = __builtin_amdgcn_mfma_f32_16x16x32_f16(
                            wh[i].b, bh[n].b, acc[i][n], 0, 0, 0);
            }
            __builtin_amdgcn_s_setprio(0);
            // ---- epilogue VALU BEFORE barrier (registers only) ----
            uint2 pk[2][4];
            #pragma unroll
            for (int i = 0; i < 2; i++) {
                int ubase = (2 * wv + i) * 16 + q * 4;
                F4 bv; bv.v = *(const float4*)&BIASB[l * 128 + ubase];
                #pragma unroll
                for (int n = 0; n < 4; n++) {
                    float t0 = fast_tanh(acc[i][n][0] + bv.f[0]);
                    float t1 = fast_tanh(acc[i][n][1] + bv.f[1]);
                    float t2 = fast_tanh(acc[i][n][2] + bv.f[2]);
                    float t3 = fast_tanh(acc[i][n][3] + bv.f[3]);
                    pk[i][n] = make_uint2(pk2(t0, t1), pk2(t2, t3));
                }
            }
            __syncthreads();
            #pragma unroll
            for (int i = 0; i < 2; i++) {
                int ubase = (2 * wv + i) * 16 + q * 4;
                #pragma unroll
                for (int n = 0; n < 4; n++)
                    *(uint2*)(ShU + (n * 16 + nn) * 136 + ubase) = pk[i][n];
            }
            __syncthreads();
        }

        // ---- layer 4 via MFMA (padded W4, hi+lo), one point-tile/wave ----
        {
            const unsigned short* W4p = wsU + 102400;
            f32x4 a4 = {0.f, 0.f, 0.f, 0.f};
            __builtin_amdgcn_s_setprio(1);
            #pragma unroll
            for (int ks = 0; ks < 4; ks++) {
                FragU bh, wh, wl;
                bh.q = *(const uint4*)(ShU + (wv * 16 + nn) * 136 + ks * 32 + q * 8);
                const unsigned short* base = W4p + ((ks * 64 + lane) << 3);
                wh.q = *(const uint4*)base;
                wl.q = *(const uint4*)(base + 2048);
                a4 = __builtin_amdgcn_mfma_f32_16x16x32_f16(wh.b, bh.b, a4, 0, 0, 0);
                a4 = __builtin_amdgcn_mfma_f32_16x16x32_f16(wl.b, bh.b, a4, 0, 0, 0);
            }
            __builtin_amdgcn_s_setprio(0);
            if (q == 0) {
                float4 o = make_float4(a4[0] + b4[0], a4[1] + b4[1],
                                       a4[2] + b4[2], a4[3] + b4[3]);
                *(float4*)&OUTB[(wv * 16 + nn) * 4] = o;
            }
        }
        __syncthreads();

        float contrib = 0.f;
        if (t < 64) {
            float o0 = OUTB[t * 4 + 0], o1 = OUTB[t * 4 + 1];
            float o2 = OUTB[t * 4 + 2], o3 = OUTB[t * 4 + 3];
            float l;
            if (batch == 0) {
                float4 Ui = *(const float4*)(U_inlet + (base_pt + t) * 4);
                float d0 = o0 - Ui.x, d1 = o1 - Ui.y, d2 = o2 - Ui.z, d3 = o3 - Ui.w;
                l = d0 * d0 + d1 * d1 + d2 * d2 + d3 * d3;
            } else if (batch == 3) {
                const float sa = -0.17364817766693033f;  // sin(-pi/18)
                const float ca =  0.9848077530122080f;   // cos(-pi/18)
                float d = -o2 * sa + o3 * ca;
                l = d * d;
            } else {
                l = o3 * o3;
            }
            contrib = 10.0f * l * (1.0f / (float)NBDY);
        }
        if (t < 64) {
            contrib += __shfl_down(contrib, 32);
            contrib += __shfl_down(contrib, 16);
            contrib += __shfl_down(contrib, 8);
            contrib += __shfl_down(contrib, 4);
            contrib += __shfl_down(contrib, 2);
            contrib += __shfl_down(contrib, 1);
            if (t == 0) atomicAdd(out, contrib);
        }
    }
}

extern "C" void kernel_launch(void* const* d_in, const int* in_sizes, int n_in,
                              void* d_out, int out_size, void* d_ws, size_t ws_size,
                              hipStream_t stream) {
    const float* xt      = (const float*)d_in[0];
    const float* x_inlet = (const float*)d_in[1];
    const float* U_inlet = (const float*)d_in[2];
    const float* x_base  = (const float*)d_in[3];
    const float* x_top   = (const float*)d_in[4];
    const float* x_slip  = (const float*)d_in[5];
    const float* W0 = (const float*)d_in[6];
    const float* b0 = (const float*)d_in[7];
    const float* W1 = (const float*)d_in[8];
    const float* b1 = (const float*)d_in[9];
    const float* W2 = (const float*)d_in[10];
    const float* b2 = (const float*)d_in[11];
    const float* W3 = (const float*)d_in[12];
    const float* b3 = (const float*)d_in[13];
    const float* W4 = (const float*)d_in[14];
    const float* b4 = (const float*)d_in[15];
    const float* V0 = (const float*)d_in[16];
    const float* c0 = (const float*)d_in[17];
    const float* V1 = (const float*)d_in[18];
    const float* c1 = (const float*)d_in[19];
    const float* V2 = (const float*)d_in[20];
    const float* c2 = (const float*)d_in[21];
    float* out = (float*)d_out;
    unsigned short* wsU = (unsigned short*)d_ws;

    pack_w_kernel<<<26, 256, 0, stream>>>(W1, W2, W3, V1, W4, wsU, out);

    fused_kernel<<<PHYS_BLOCKS + BDY_BLOCKS, 256, 0, stream>>>(
        xt, x_inlet, U_inlet, x_base, x_top, x_slip,
        W0, b0, W1, b1, W2, b2, W3, b3, W4, b4,
        V0, c0, V1, c1, V2, c2, wsU, out);
}